// Round 1
// baseline (806.296 us; speedup 1.0000x reference)
//
#include <hip/hip_runtime.h>
#include <math.h>

// BVP Helmholtz-residual PINN via MFMA, round 7.
// Round-6 post-mortem: MfmaUtil 44.6% == exactly the MFMA-pipe busy time
// (16x16x32 bf16 ~19.4 cy/SIMD -> 114 us floor); VALUBusy 65% = MFMA(45%)
// + true VALU(~20%); LDS pipe ~42%. Pipes sum to ~107% of wall time ->
// phases run nearly serially (barrier convoying, co-resident blocks often
// in-phase). Round-7: two-group ping-pong pipeline in one 1024-thread
// block. Waves 0-7 = group A, 8-15 = group B (round-robin wave->SIMD =
// 2+2 per SIMD). B runs one stage behind A, so every super-phase pairs
// one group's GEMM (MFMA) with the other's layer/jet (VALU):
//   p1 A.L1|-, p2 A.G2|B.L1, p3 A.J2|B.G2, p4 A.G3|B.J2, p5 A.J3|B.G3,
//   p6 -|B.J3.  Per-group Bsh/red; full-block barriers protect all edges.
// LDS 122880 B -> 1 block/CU (16 waves, same as before, now complementary).

typedef __attribute__((ext_vector_type(8))) short short8;
typedef __attribute__((ext_vector_type(4))) float floatx4;
typedef unsigned short ushort_t;
typedef unsigned int uint_t;

#define PBLK 32   // points per block: 2 pipelined groups of 16

__device__ __forceinline__ ushort_t f2bf(float f) {
    uint_t u = __float_as_uint(f);
    return (ushort_t)((u + 0x7FFFu + ((u >> 16) & 1u)) >> 16);  // RNE
}
// pack2bf(f0,f1): {bf16(f0), bf16(f1)} in one u32 (f0 low). Round-half-up.
__device__ __forceinline__ uint_t pack2bf(float f0, float f1) {
    uint_t u0 = __float_as_uint(f0) + 0x8000u;
    uint_t u1 = __float_as_uint(f1) + 0x8000u;
    return __builtin_amdgcn_perm(u1, u0, 0x07060302u);
}
__device__ __forceinline__ float fast_tanh(float u) {
    float e = __expf(2.f * u);
    return 1.f - 2.f / (e + 1.f);   // exact at +-inf for finite u
}

// ws: 2 layers x 16 row-tiles x 8 kc x 64 lanes x 16B = 256 KB.
// A-frag lane (m=lane&15, qa=lane>>4) slot j:
//   layer0 (W2, natural):  col = kc*32 + 8*qa + j
//   layer1 (W3, permuted): col = kc*32 + 16*(j>>2) + 4*qa + (j&3)
__global__ void prep_split(const float* __restrict__ W2, const float* __restrict__ W3,
                           short8* __restrict__ ws) {
    int t16 = blockIdx.x * blockDim.x + threadIdx.x;  // 0..16383
    int lane = t16 & 63;
    int kc = (t16 >> 6) & 7;
    int tt = (t16 >> 9) & 15;
    int l = t16 >> 13;
    const float* W = l ? W3 : W2;
    int row = tt * 16 + (lane & 15);
    int qa = lane >> 4;
    const float* src = W + row * 256 + kc * 32 + (l ? 4 * qa : 8 * qa);
    float4 va = *(const float4*)src;
    float4 vb = *(const float4*)(src + (l ? 16 : 4));
    float v[8] = {va.x, va.y, va.z, va.w, vb.x, vb.y, vb.z, vb.w};
    short8 hi8;
    #pragma unroll
    for (int j = 0; j < 8; ++j) hi8[j] = (short)f2bf(v[j]);   // RNE (runs once)
    ws[l * 8192 + tt * 512 + kc * 64 + lane] = hi8;
}

__global__ __launch_bounds__(1024, 4)
void bvp_main(const float* __restrict__ gx, const float* __restrict__ gy,
              const float* __restrict__ gz, const float* __restrict__ gf,
              const float* __restrict__ W1, const float* __restrict__ b1,
              const float* __restrict__ b2, const float* __restrict__ b3,
              const float* __restrict__ W4, const float* __restrict__ b4,
              const short8* __restrict__ wsA, float* __restrict__ out, int N) {
    __shared__ short8 Bsh[2][7 * 8 * 64];   // 114688 B: per-group B[s][kt][lane]
    __shared__ float red[2][8][16][8];      // 8192 B: per-group reduction scratch

    const int tid = threadIdx.x;
    const int w = tid >> 6, lane = tid & 63;
    const int grp = w >> 3;            // waves 0-7: group A, 8-15: group B
    const int wl = w & 7;              // wave-in-group
    const int gt = tid & 511;          // thread-in-group
    const int n15 = lane & 15, qc = lane >> 4;
    const int pbase = blockIdx.x * PBLK + grp * 16;
    short8* const __restrict__ Bg = Bsh[grp];
    const short8* const __restrict__ wsA3 = wsA + 8192;

    floatx4 acc[2][7];   // 2 row-tiles (32 rows) x 7 streams
    short8 a0[2], a1[2];

    // K-loop: A 1-deep global prefetch (L2-resident), B single-buffer LDS.
    auto run_gemm = [&](const short8* __restrict__ A) {
        #pragma unroll
        for (int rt = 0; rt < 2; ++rt)
            #pragma unroll
            for (int ct = 0; ct < 7; ++ct) acc[rt][ct] = (floatx4){0.f, 0.f, 0.f, 0.f};
        #pragma unroll
        for (int kc = 0; kc < 8; ++kc) {
            if (kc < 7) {
                #pragma unroll
                for (int rt = 0; rt < 2; ++rt)
                    a1[rt] = A[(2 * wl + rt) * 512 + (kc + 1) * 64 + lane];
            }
            short8 b[7];
            #pragma unroll
            for (int ct = 0; ct < 7; ++ct) b[ct] = Bg[(ct * 8 + kc) * 64 + lane];
            #pragma unroll
            for (int ct = 0; ct < 7; ++ct)
                #pragma unroll
                for (int rt = 0; rt < 2; ++rt)
                    acc[rt][ct] = __builtin_amdgcn_mfma_f32_16x16x32_bf16(a0[rt], b[ct], acc[rt][ct], 0, 0, 0);
            if (kc < 7) {
                #pragma unroll
                for (int rt = 0; rt < 2; ++rt) a0[rt] = a1[rt];
            }
        }
    };

    // ---------------- layer 1 (VALU) -> B fragments ----------------
    // pp = gt&15: 16-lane groups write contiguous 256B -> conflict-free;
    // threads sharing u8 read the same W1 rows (broadcast).
    auto stage_l1 = [&]() {
        // GEMM-2 A(kc=0): issue now, covered by layer-1 math.
        #pragma unroll
        for (int rt = 0; rt < 2; ++rt) a0[rt] = wsA[(2 * wl + rt) * 512 + lane];
        const int pp = gt & 15, u8 = gt >> 4;   // u8 in 0..31: neurons 8*u8..+7
        const int pidx = min(pbase + pp, N - 1);
        const float xi = gx[pidx], yi = gy[pidx], zi = gz[pidx], fi = gf[pidx];
        float hv[7][8];
        #pragma unroll
        for (int r = 0; r < 8; ++r) {
            const int i = u8 * 8 + r;
            float4 wv = *(const float4*)(W1 + 4 * i);
            float u = fmaf(wv.x, xi, fmaf(wv.y, yi, fmaf(wv.z, zi, fmaf(wv.w, fi, b1[i]))));
            float t = fast_tanh(u), s = 1.f - t * t, c = -2.f * t * s;
            hv[0][r] = t;
            hv[1][r] = s * wv.x; hv[2][r] = s * wv.y; hv[3][r] = s * wv.z;
            hv[4][r] = c * wv.x * wv.x; hv[5][r] = c * wv.y * wv.y; hv[6][r] = c * wv.z * wv.z;
        }
        const int kt = u8 >> 2, qb = u8 & 3;    // k-slot qb*8+r (natural order)
        #pragma unroll
        for (int s = 0; s < 7; ++s) {
            union { short8 s8; uint_t u4[4]; } v;
            #pragma unroll
            for (int j = 0; j < 4; ++j)
                v.u4[j] = pack2bf(hv[s][2 * j], hv[s][2 * j + 1]);
            Bg[(s * 8 + kt) * 64 + qb * 16 + pp] = v.s8;
        }
    };

    // ---------------- jet 2 (lane-local) -> new B fragments ----------------
    // Wave wl's 32 rows are exactly k-tile wl; permuted k-order
    // k(qc,j)=16(j>>2)+4qc+(j&3) makes the repack lane-local.
    auto stage_j2 = [&]() {
        // GEMM-3 A(kc=0): issue now, covered by jet-2 math.
        #pragma unroll
        for (int rt = 0; rt < 2; ++rt) a0[rt] = wsA3[(2 * wl + rt) * 512 + lane];
        #pragma unroll
        for (int rt = 0; rt < 2; ++rt) {
            const float4 bb = *(const float4*)(b2 + wl * 32 + rt * 16 + qc * 4);
            const float bbv[4] = {bb.x, bb.y, bb.z, bb.w};
            #pragma unroll
            for (int r = 0; r < 4; ++r) {
                float t = fast_tanh(acc[rt][0][r] + bbv[r]);
                float s = 1.f - t * t, c = -2.f * t * s;
                float ux = acc[rt][1][r], uy = acc[rt][2][r], uz = acc[rt][3][r];
                acc[rt][0][r] = t;
                acc[rt][1][r] = s * ux; acc[rt][2][r] = s * uy; acc[rt][3][r] = s * uz;
                acc[rt][4][r] = fmaf(s, acc[rt][4][r], c * ux * ux);
                acc[rt][5][r] = fmaf(s, acc[rt][5][r], c * uy * uy);
                acc[rt][6][r] = fmaf(s, acc[rt][6][r], c * uz * uz);
            }
        }
        #pragma unroll
        for (int s = 0; s < 7; ++s) {
            union { short8 s8; uint_t u4[4]; } v;
            v.u4[0] = pack2bf(acc[0][s][0], acc[0][s][1]);
            v.u4[1] = pack2bf(acc[0][s][2], acc[0][s][3]);
            v.u4[2] = pack2bf(acc[1][s][0], acc[1][s][1]);
            v.u4[3] = pack2bf(acc[1][s][2], acc[1][s][3]);
            Bg[(s * 8 + wl) * 64 + lane] = v.s8;   // kt = wl, own lane slot
        }
    };

    // ---------------- jet 3 + layer-4 partials (lane-local) ----------------
    auto stage_j3 = [&]() {
        float pt[8] = {0.f, 0.f, 0.f, 0.f, 0.f, 0.f, 0.f, 0.f};
        #pragma unroll
        for (int rt = 0; rt < 2; ++rt) {
            const int rb = wl * 32 + rt * 16 + qc * 4;
            const float4 bb = *(const float4*)(b3 + rb);
            const float4 w0 = *(const float4*)(W4 + rb);
            const float4 w1 = *(const float4*)(W4 + 256 + rb);
            const float bbv[4] = {bb.x, bb.y, bb.z, bb.w};
            const float w0v[4] = {w0.x, w0.y, w0.z, w0.w};
            const float w1v[4] = {w1.x, w1.y, w1.z, w1.w};
            #pragma unroll
            for (int r = 0; r < 4; ++r) {
                float t = fast_tanh(acc[rt][0][r] + bbv[r]);
                float s = 1.f - t * t, c = -2.f * t * s;
                float ux = acc[rt][1][r], uy = acc[rt][2][r], uz = acc[rt][3][r];
                float hvv = t;
                float hxx = fmaf(s, acc[rt][4][r], c * ux * ux);
                float hyy = fmaf(s, acc[rt][5][r], c * uy * uy);
                float hzz = fmaf(s, acc[rt][6][r], c * uz * uz);
                pt[0] = fmaf(w0v[r], hvv, pt[0]);
                pt[1] = fmaf(w0v[r], hxx, pt[1]);
                pt[2] = fmaf(w0v[r], hyy, pt[2]);
                pt[3] = fmaf(w0v[r], hzz, pt[3]);
                pt[4] = fmaf(w1v[r], hvv, pt[4]);
                pt[5] = fmaf(w1v[r], hxx, pt[5]);
                pt[6] = fmaf(w1v[r], hyy, pt[6]);
                pt[7] = fmaf(w1v[r], hzz, pt[7]);
            }
        }
        #pragma unroll
        for (int k = 0; k < 8; ++k) {
            pt[k] += __shfl_xor(pt[k], 16, 64);
            pt[k] += __shfl_xor(pt[k], 32, 64);
        }
        if (qc == 0) {
            *(float4*)&red[grp][wl][n15][0] = make_float4(pt[0], pt[1], pt[2], pt[3]);
            *(float4*)&red[grp][wl][n15][4] = make_float4(pt[4], pt[5], pt[6], pt[7]);
        }
    };

    // ---------------- 6-super-phase ping-pong pipeline ----------------
    // Group grp executes stage st = ph - grp at super-phase ph. Every
    // producer->consumer edge (L1->G2, G2->J2 buffer reuse, J2->G3) is
    // separated by a full-block barrier; the two groups touch disjoint
    // Bsh/red halves, so cross-group phases are race-free.
    #pragma unroll 1
    for (int ph = 0; ph < 6; ++ph) {
        const int st = ph - grp;
        if (st == 0)      stage_l1();
        else if (st == 1) run_gemm(wsA);
        else if (st == 2) stage_j2();
        else if (st == 3) run_gemm(wsA3);
        else if (st == 4) stage_j3();
        __syncthreads();
    }

    // ---------------- final cross-wave reduction + residual ----------------
    if (gt < 16 && (pbase + gt) < N) {
        const int n = pbase + gt;
        float s8[8] = {0.f, 0.f, 0.f, 0.f, 0.f, 0.f, 0.f, 0.f};
        #pragma unroll
        for (int ww = 0; ww < 8; ++ww)
            #pragma unroll
            for (int k = 0; k < 8; ++k) s8[k] += red[grp][ww][gt][k];
        const float fi = gf[n];
        const float PI = 3.14159265358979323846f;
        const float kw = 2.f * PI * (fi * 500.f + 100.f) / 343.f;
        const float vol = 0.7f * 0.5f * 0.6f;
        const float kk = vol * vol * kw * kw;
        const float cxx = (0.5f * 0.6f) * (0.5f * 0.6f);
        const float cyy = (0.7f * 0.6f) * (0.7f * 0.6f);
        const float czz = (0.7f * 0.5f) * (0.7f * 0.5f);
        const float pr = s8[0] + b4[0];
        const float pim = s8[4] + b4[1];
        out[n]     = 2.0f * (cxx * s8[1] + cyy * s8[2] + czz * s8[3]) + kk * (pr * 2.0f + 0.1f);
        out[N + n] = 1.5f * (cxx * s8[5] + cyy * s8[6] + czz * s8[7]) + kk * (pim * 1.5f - 0.05f);
    }
}

extern "C" void kernel_launch(void* const* d_in, const int* in_sizes, int n_in,
                              void* d_out, int out_size, void* d_ws, size_t ws_size,
                              hipStream_t stream) {
    const float* x = (const float*)d_in[0];
    const float* y = (const float*)d_in[1];
    const float* z = (const float*)d_in[2];
    const float* f = (const float*)d_in[3];
    const float* W1 = (const float*)d_in[4];
    const float* b1 = (const float*)d_in[5];
    const float* W2 = (const float*)d_in[6];
    const float* b2 = (const float*)d_in[7];
    const float* W3 = (const float*)d_in[8];
    const float* b3 = (const float*)d_in[9];
    const float* W4 = (const float*)d_in[10];
    const float* b4 = (const float*)d_in[11];
    float* out = (float*)d_out;
    const int N = in_sizes[0];
    const int grid = (N + PBLK - 1) / PBLK;

    prep_split<<<64, 256, 0, stream>>>(W2, W3, (short8*)d_ws);
    bvp_main<<<grid, 1024, 0, stream>>>(x, y, z, f, W1, b1, b2, b3, W4, b4,
                                        (const short8*)d_ws, out, N);
}

// Round 2
// 351.148 us; speedup vs baseline: 2.2962x; 2.2962x over previous
//
#include <hip/hip_runtime.h>
#include <math.h>

// BVP Helmholtz-residual PINN via MFMA, round 8.
// Round-7 post-mortem: the rolled phase loop (#pragma unroll 1 + branch-
// dependent stage dispatch) forced acc[2][7] into scratch -> 2.2 GB HBM
// spill traffic (WRITE_SIZE 1.4 GB), MfmaUtil 12.9%, 782 us. Theory not
// tested. Round-8: SAME two-group ping-pong, but straight-line phases:
//   ph0 A.L1|-      ph1 A.G2|B.L1   ph2 A.J2|B.G2
//   ph3 A.G3|B.J2   ph4 A.J3|B.G3   ph5  -  |B.J3
// Every stage sits under wave-uniform `if (grp==..)` at top level; all
// __syncthreads() uniform; acc live ranges are plain across-barrier
// register ranges (same as round 6, which did not spill).

typedef __attribute__((ext_vector_type(8))) short short8;
typedef __attribute__((ext_vector_type(4))) float floatx4;
typedef unsigned short ushort_t;
typedef unsigned int uint_t;

#define PBLK 32   // points per block: 2 pipelined groups of 16

__device__ __forceinline__ ushort_t f2bf(float f) {
    uint_t u = __float_as_uint(f);
    return (ushort_t)((u + 0x7FFFu + ((u >> 16) & 1u)) >> 16);  // RNE
}
// pack2bf(f0,f1): {bf16(f0), bf16(f1)} in one u32 (f0 low). Round-half-up.
__device__ __forceinline__ uint_t pack2bf(float f0, float f1) {
    uint_t u0 = __float_as_uint(f0) + 0x8000u;
    uint_t u1 = __float_as_uint(f1) + 0x8000u;
    return __builtin_amdgcn_perm(u1, u0, 0x07060302u);
}
__device__ __forceinline__ float fast_tanh(float u) {
    float e = __expf(2.f * u);
    return 1.f - 2.f / (e + 1.f);   // exact at +-inf for finite u
}

// ws: 2 layers x 16 row-tiles x 8 kc x 64 lanes x 16B = 256 KB.
// A-frag lane (m=lane&15, qa=lane>>4) slot j:
//   layer0 (W2, natural):  col = kc*32 + 8*qa + j
//   layer1 (W3, permuted): col = kc*32 + 16*(j>>2) + 4*qa + (j&3)
__global__ void prep_split(const float* __restrict__ W2, const float* __restrict__ W3,
                           short8* __restrict__ ws) {
    int t16 = blockIdx.x * blockDim.x + threadIdx.x;  // 0..16383
    int lane = t16 & 63;
    int kc = (t16 >> 6) & 7;
    int tt = (t16 >> 9) & 15;
    int l = t16 >> 13;
    const float* W = l ? W3 : W2;
    int row = tt * 16 + (lane & 15);
    int qa = lane >> 4;
    const float* src = W + row * 256 + kc * 32 + (l ? 4 * qa : 8 * qa);
    float4 va = *(const float4*)src;
    float4 vb = *(const float4*)(src + (l ? 16 : 4));
    float v[8] = {va.x, va.y, va.z, va.w, vb.x, vb.y, vb.z, vb.w};
    short8 hi8;
    #pragma unroll
    for (int j = 0; j < 8; ++j) hi8[j] = (short)f2bf(v[j]);   // RNE (runs once)
    ws[l * 8192 + tt * 512 + kc * 64 + lane] = hi8;
}

__global__ __launch_bounds__(1024, 4)
void bvp_main(const float* __restrict__ gx, const float* __restrict__ gy,
              const float* __restrict__ gz, const float* __restrict__ gf,
              const float* __restrict__ W1, const float* __restrict__ b1,
              const float* __restrict__ b2, const float* __restrict__ b3,
              const float* __restrict__ W4, const float* __restrict__ b4,
              const short8* __restrict__ wsA, float* __restrict__ out, int N) {
    __shared__ short8 Bsh[2][7 * 8 * 64];   // 114688 B: per-group B[s][kt][lane]
    __shared__ float red[2][8][16][8];      // 8192 B: per-group reduction scratch

    const int tid = threadIdx.x;
    const int w = tid >> 6, lane = tid & 63;
    const int grp = w >> 3;            // waves 0-7: group A, 8-15: group B
    const int wl = w & 7;              // wave-in-group
    const int gt = tid & 511;          // thread-in-group
    const int n15 = lane & 15, qc = lane >> 4;
    const int pbase = blockIdx.x * PBLK + grp * 16;
    short8* const __restrict__ Bg = Bsh[grp];
    const short8* const __restrict__ wsA3 = wsA + 8192;

    floatx4 acc[2][7];   // 2 row-tiles (32 rows) x 7 streams
    short8 a0[2], a1[2];

    // K-loop: A 1-deep global prefetch (L2-resident), B single-buffer LDS.
    auto run_gemm = [&](const short8* __restrict__ A) {
        #pragma unroll
        for (int rt = 0; rt < 2; ++rt)
            #pragma unroll
            for (int ct = 0; ct < 7; ++ct) acc[rt][ct] = (floatx4){0.f, 0.f, 0.f, 0.f};
        #pragma unroll
        for (int kc = 0; kc < 8; ++kc) {
            if (kc < 7) {
                #pragma unroll
                for (int rt = 0; rt < 2; ++rt)
                    a1[rt] = A[(2 * wl + rt) * 512 + (kc + 1) * 64 + lane];
            }
            short8 b[7];
            #pragma unroll
            for (int ct = 0; ct < 7; ++ct) b[ct] = Bg[(ct * 8 + kc) * 64 + lane];
            #pragma unroll
            for (int ct = 0; ct < 7; ++ct)
                #pragma unroll
                for (int rt = 0; rt < 2; ++rt)
                    acc[rt][ct] = __builtin_amdgcn_mfma_f32_16x16x32_bf16(a0[rt], b[ct], acc[rt][ct], 0, 0, 0);
            if (kc < 7) {
                #pragma unroll
                for (int rt = 0; rt < 2; ++rt) a0[rt] = a1[rt];
            }
        }
    };

    // ---------------- layer 1 (VALU) -> B fragments ----------------
    // pp = gt&15: 16-lane groups write contiguous 256B -> conflict-free;
    // threads sharing u8 read the same W1 rows (broadcast).
    auto stage_l1 = [&]() {
        // GEMM-2 A(kc=0): issue now, covered by layer-1 math.
        #pragma unroll
        for (int rt = 0; rt < 2; ++rt) a0[rt] = wsA[(2 * wl + rt) * 512 + lane];
        const int pp = gt & 15, u8 = gt >> 4;   // u8 in 0..31: neurons 8*u8..+7
        const int pidx = min(pbase + pp, N - 1);
        const float xi = gx[pidx], yi = gy[pidx], zi = gz[pidx], fi = gf[pidx];
        float hv[7][8];
        #pragma unroll
        for (int r = 0; r < 8; ++r) {
            const int i = u8 * 8 + r;
            float4 wv = *(const float4*)(W1 + 4 * i);
            float u = fmaf(wv.x, xi, fmaf(wv.y, yi, fmaf(wv.z, zi, fmaf(wv.w, fi, b1[i]))));
            float t = fast_tanh(u), s = 1.f - t * t, c = -2.f * t * s;
            hv[0][r] = t;
            hv[1][r] = s * wv.x; hv[2][r] = s * wv.y; hv[3][r] = s * wv.z;
            hv[4][r] = c * wv.x * wv.x; hv[5][r] = c * wv.y * wv.y; hv[6][r] = c * wv.z * wv.z;
        }
        const int kt = u8 >> 2, qb = u8 & 3;    // k-slot qb*8+r (natural order)
        #pragma unroll
        for (int s = 0; s < 7; ++s) {
            union { short8 s8; uint_t u4[4]; } v;
            #pragma unroll
            for (int j = 0; j < 4; ++j)
                v.u4[j] = pack2bf(hv[s][2 * j], hv[s][2 * j + 1]);
            Bg[(s * 8 + kt) * 64 + qb * 16 + pp] = v.s8;
        }
    };

    // ---------------- jet 2 (lane-local) -> new B fragments ----------------
    // Wave wl's 32 rows are exactly k-tile wl; permuted k-order
    // k(qc,j)=16(j>>2)+4qc+(j&3) makes the repack lane-local.
    auto stage_j2 = [&]() {
        // GEMM-3 A(kc=0): issue now, covered by jet-2 math.
        #pragma unroll
        for (int rt = 0; rt < 2; ++rt) a0[rt] = wsA3[(2 * wl + rt) * 512 + lane];
        #pragma unroll
        for (int rt = 0; rt < 2; ++rt) {
            const float4 bb = *(const float4*)(b2 + wl * 32 + rt * 16 + qc * 4);
            const float bbv[4] = {bb.x, bb.y, bb.z, bb.w};
            #pragma unroll
            for (int r = 0; r < 4; ++r) {
                float t = fast_tanh(acc[rt][0][r] + bbv[r]);
                float s = 1.f - t * t, c = -2.f * t * s;
                float ux = acc[rt][1][r], uy = acc[rt][2][r], uz = acc[rt][3][r];
                acc[rt][0][r] = t;
                acc[rt][1][r] = s * ux; acc[rt][2][r] = s * uy; acc[rt][3][r] = s * uz;
                acc[rt][4][r] = fmaf(s, acc[rt][4][r], c * ux * ux);
                acc[rt][5][r] = fmaf(s, acc[rt][5][r], c * uy * uy);
                acc[rt][6][r] = fmaf(s, acc[rt][6][r], c * uz * uz);
            }
        }
        #pragma unroll
        for (int s = 0; s < 7; ++s) {
            union { short8 s8; uint_t u4[4]; } v;
            v.u4[0] = pack2bf(acc[0][s][0], acc[0][s][1]);
            v.u4[1] = pack2bf(acc[0][s][2], acc[0][s][3]);
            v.u4[2] = pack2bf(acc[1][s][0], acc[1][s][1]);
            v.u4[3] = pack2bf(acc[1][s][2], acc[1][s][3]);
            Bg[(s * 8 + wl) * 64 + lane] = v.s8;   // kt = wl, own lane slot
        }
    };

    // ---------------- jet 3 + layer-4 partials (lane-local) ----------------
    auto stage_j3 = [&]() {
        float pt[8] = {0.f, 0.f, 0.f, 0.f, 0.f, 0.f, 0.f, 0.f};
        #pragma unroll
        for (int rt = 0; rt < 2; ++rt) {
            const int rb = wl * 32 + rt * 16 + qc * 4;
            const float4 bb = *(const float4*)(b3 + rb);
            const float4 w0 = *(const float4*)(W4 + rb);
            const float4 w1 = *(const float4*)(W4 + 256 + rb);
            const float bbv[4] = {bb.x, bb.y, bb.z, bb.w};
            const float w0v[4] = {w0.x, w0.y, w0.z, w0.w};
            const float w1v[4] = {w1.x, w1.y, w1.z, w1.w};
            #pragma unroll
            for (int r = 0; r < 4; ++r) {
                float t = fast_tanh(acc[rt][0][r] + bbv[r]);
                float s = 1.f - t * t, c = -2.f * t * s;
                float ux = acc[rt][1][r], uy = acc[rt][2][r], uz = acc[rt][3][r];
                float hvv = t;
                float hxx = fmaf(s, acc[rt][4][r], c * ux * ux);
                float hyy = fmaf(s, acc[rt][5][r], c * uy * uy);
                float hzz = fmaf(s, acc[rt][6][r], c * uz * uz);
                pt[0] = fmaf(w0v[r], hvv, pt[0]);
                pt[1] = fmaf(w0v[r], hxx, pt[1]);
                pt[2] = fmaf(w0v[r], hyy, pt[2]);
                pt[3] = fmaf(w0v[r], hzz, pt[3]);
                pt[4] = fmaf(w1v[r], hvv, pt[4]);
                pt[5] = fmaf(w1v[r], hxx, pt[5]);
                pt[6] = fmaf(w1v[r], hyy, pt[6]);
                pt[7] = fmaf(w1v[r], hzz, pt[7]);
            }
        }
        #pragma unroll
        for (int k = 0; k < 8; ++k) {
            pt[k] += __shfl_xor(pt[k], 16, 64);
            pt[k] += __shfl_xor(pt[k], 32, 64);
        }
        if (qc == 0) {
            *(float4*)&red[grp][wl][n15][0] = make_float4(pt[0], pt[1], pt[2], pt[3]);
            *(float4*)&red[grp][wl][n15][4] = make_float4(pt[4], pt[5], pt[6], pt[7]);
        }
    };

    // ---------------- 6-phase ping-pong, straight-line ----------------
    // Wave-uniform grp branches; all barriers at top level (uniform).
    // ph0: A.L1 | -
    if (grp == 0) stage_l1();
    __syncthreads();
    // ph1: A.G2 | B.L1
    if (grp == 0) run_gemm(wsA); else stage_l1();
    __syncthreads();
    // ph2: A.J2 | B.G2
    if (grp == 0) stage_j2(); else run_gemm(wsA);
    __syncthreads();
    // ph3: A.G3 | B.J2
    if (grp == 0) run_gemm(wsA3); else stage_j2();
    __syncthreads();
    // ph4: A.J3 | B.G3
    if (grp == 0) stage_j3(); else run_gemm(wsA3);
    __syncthreads();
    // ph5: -    | B.J3
    if (grp == 1) stage_j3();
    __syncthreads();

    // ---------------- final cross-wave reduction + residual ----------------
    if (gt < 16 && (pbase + gt) < N) {
        const int n = pbase + gt;
        float s8[8] = {0.f, 0.f, 0.f, 0.f, 0.f, 0.f, 0.f, 0.f};
        #pragma unroll
        for (int ww = 0; ww < 8; ++ww)
            #pragma unroll
            for (int k = 0; k < 8; ++k) s8[k] += red[grp][ww][gt][k];
        const float fi = gf[n];
        const float PI = 3.14159265358979323846f;
        const float kw = 2.f * PI * (fi * 500.f + 100.f) / 343.f;
        const float vol = 0.7f * 0.5f * 0.6f;
        const float kk = vol * vol * kw * kw;
        const float cxx = (0.5f * 0.6f) * (0.5f * 0.6f);
        const float cyy = (0.7f * 0.6f) * (0.7f * 0.6f);
        const float czz = (0.7f * 0.5f) * (0.7f * 0.5f);
        const float pr = s8[0] + b4[0];
        const float pim = s8[4] + b4[1];
        out[n]     = 2.0f * (cxx * s8[1] + cyy * s8[2] + czz * s8[3]) + kk * (pr * 2.0f + 0.1f);
        out[N + n] = 1.5f * (cxx * s8[5] + cyy * s8[6] + czz * s8[7]) + kk * (pim * 1.5f - 0.05f);
    }
}

extern "C" void kernel_launch(void* const* d_in, const int* in_sizes, int n_in,
                              void* d_out, int out_size, void* d_ws, size_t ws_size,
                              hipStream_t stream) {
    const float* x = (const float*)d_in[0];
    const float* y = (const float*)d_in[1];
    const float* z = (const float*)d_in[2];
    const float* f = (const float*)d_in[3];
    const float* W1 = (const float*)d_in[4];
    const float* b1 = (const float*)d_in[5];
    const float* W2 = (const float*)d_in[6];
    const float* b2 = (const float*)d_in[7];
    const float* W3 = (const float*)d_in[8];
    const float* b3 = (const float*)d_in[9];
    const float* W4 = (const float*)d_in[10];
    const float* b4 = (const float*)d_in[11];
    float* out = (float*)d_out;
    const int N = in_sizes[0];
    const int grid = (N + PBLK - 1) / PBLK;

    prep_split<<<64, 256, 0, stream>>>(W2, W3, (short8*)d_ws);
    bvp_main<<<grid, 1024, 0, stream>>>(x, y, z, f, W1, b1, b2, b3, W4, b4,
                                        (const short8*)d_ws, out, N);
}

// Round 3
// 320.971 us; speedup vs baseline: 2.5120x; 1.0940x over previous
//
#include <hip/hip_runtime.h>
#include <math.h>

// BVP Helmholtz-residual PINN via MFMA, round 9.
// Round-8 post-mortem: lockstep ping-pong FAILED (320 vs 256 us). During a
// GEMM phase only 2 waves/SIMD issue MFMA -> ~36% pipe eff (== measured
// MfmaUtil 34.7). Round-6's free drift sometimes overlaps two blocks' GEMMs
// (4 waves/SIMD -> 45%). Revised theory: GEMM K-loop is LDS-latency-bound
// per wave; compiler can't pipeline B across kc because b[7] (28 VGPR) +
// the 128-reg cap leave no headroom (why round-5 "manual ILP" was neutral).
// Round-9: revert to round-6 structure; flatten the K-loop to 56 (kc,ct)
// steps with a rotating 4-deep B prefetch: live B regs 28 -> 16, B
// issue-to-use distance = 8 MFMAs (~155 cy) > LDS latency (~120 cy).

typedef __attribute__((ext_vector_type(8))) short short8;
typedef __attribute__((ext_vector_type(4))) float floatx4;
typedef unsigned short ushort_t;
typedef unsigned int uint_t;

#define PBLK 16

__device__ __forceinline__ ushort_t f2bf(float f) {
    uint_t u = __float_as_uint(f);
    return (ushort_t)((u + 0x7FFFu + ((u >> 16) & 1u)) >> 16);  // RNE
}
// pack2bf(f0,f1): {bf16(f0), bf16(f1)} in one u32 (f0 low). Round-half-up.
__device__ __forceinline__ uint_t pack2bf(float f0, float f1) {
    uint_t u0 = __float_as_uint(f0) + 0x8000u;
    uint_t u1 = __float_as_uint(f1) + 0x8000u;
    return __builtin_amdgcn_perm(u1, u0, 0x07060302u);
}
__device__ __forceinline__ float fast_tanh(float u) {
    float e = __expf(2.f * u);
    return 1.f - 2.f / (e + 1.f);   // exact at +-inf for finite u
}

// ws: 2 layers x 16 row-tiles x 8 kc x 64 lanes x 16B = 256 KB.
// A-frag lane (m=lane&15, qa=lane>>4) slot j:
//   layer0 (W2, natural):  col = kc*32 + 8*qa + j
//   layer1 (W3, permuted): col = kc*32 + 16*(j>>2) + 4*qa + (j&3)
__global__ void prep_split(const float* __restrict__ W2, const float* __restrict__ W3,
                           short8* __restrict__ ws) {
    int t16 = blockIdx.x * blockDim.x + threadIdx.x;  // 0..16383
    int lane = t16 & 63;
    int kc = (t16 >> 6) & 7;
    int tt = (t16 >> 9) & 15;
    int l = t16 >> 13;
    const float* W = l ? W3 : W2;
    int row = tt * 16 + (lane & 15);
    int qa = lane >> 4;
    const float* src = W + row * 256 + kc * 32 + (l ? 4 * qa : 8 * qa);
    float4 va = *(const float4*)src;
    float4 vb = *(const float4*)(src + (l ? 16 : 4));
    float v[8] = {va.x, va.y, va.z, va.w, vb.x, vb.y, vb.z, vb.w};
    short8 hi8;
    #pragma unroll
    for (int j = 0; j < 8; ++j) hi8[j] = (short)f2bf(v[j]);   // RNE (runs once)
    ws[l * 8192 + tt * 512 + kc * 64 + lane] = hi8;
}

__global__ __launch_bounds__(512, 4)
void bvp_main(const float* __restrict__ gx, const float* __restrict__ gy,
              const float* __restrict__ gz, const float* __restrict__ gf,
              const float* __restrict__ W1, const float* __restrict__ b1,
              const float* __restrict__ b2, const float* __restrict__ b3,
              const float* __restrict__ W4, const float* __restrict__ b4,
              const short8* __restrict__ wsA, float* __restrict__ out, int N) {
    __shared__ short8 Bsh[7 * 8 * 64];   // 57344 B: B[s][kt][lane]
    __shared__ float red[8][16][8];      // 4 KB cross-wave reduction scratch

    const int tid = threadIdx.x;
    const int w = tid >> 6, lane = tid & 63;
    const int n15 = lane & 15, qc = lane >> 4;
    const int pbase = blockIdx.x * PBLK;
    const short8* __restrict__ wsA3 = wsA + 8192;

    floatx4 acc[2][7];   // 2 row-tiles (32 rows) x 7 streams
    short8 a0[2], a1[2];

    // GEMM-2 A(kc=0): issue now, covered by layer-1 math.
    #pragma unroll
    for (int rt = 0; rt < 2; ++rt) a0[rt] = wsA[(2 * w + rt) * 512 + lane];

    // ---------------- layer 1 (VALU) -> B fragments ----------------
    // pp = tid&15: 16-lane groups write contiguous 256B -> conflict-free;
    // threads sharing u8 read the same W1 rows (broadcast).
    {
        const int pp = tid & 15, u8 = tid >> 4;     // u8 in 0..31: neurons 8*u8..+7
        const int pidx = min(pbase + pp, N - 1);
        const float xi = gx[pidx], yi = gy[pidx], zi = gz[pidx], fi = gf[pidx];
        float hv[7][8];
        #pragma unroll
        for (int r = 0; r < 8; ++r) {
            const int i = u8 * 8 + r;
            float4 wv = *(const float4*)(W1 + 4 * i);
            float u = fmaf(wv.x, xi, fmaf(wv.y, yi, fmaf(wv.z, zi, fmaf(wv.w, fi, b1[i]))));
            float t = fast_tanh(u), s = 1.f - t * t, c = -2.f * t * s;
            hv[0][r] = t;
            hv[1][r] = s * wv.x; hv[2][r] = s * wv.y; hv[3][r] = s * wv.z;
            hv[4][r] = c * wv.x * wv.x; hv[5][r] = c * wv.y * wv.y; hv[6][r] = c * wv.z * wv.z;
        }
        const int kt = u8 >> 2, qb = u8 & 3;        // k-slot qb*8+r (natural order)
        #pragma unroll
        for (int s = 0; s < 7; ++s) {
            union { short8 s8; uint_t u4[4]; } v;
            #pragma unroll
            for (int j = 0; j < 4; ++j)
                v.u4[j] = pack2bf(hv[s][2 * j], hv[s][2 * j + 1]);
            Bsh[(s * 8 + kt) * 64 + qb * 16 + pp] = v.s8;
        }
    }
    __syncthreads();

    // Flattened K-loop: 56 (kc,ct) steps, rotating 4-deep B prefetch
    // (live B = 16 VGPR vs 28 for b[7] -> fits the 128-reg cap with room;
    // B issue-to-use distance = 8 MFMAs). A keeps the 1-deep prefetch.
    auto run_gemm = [&](const short8* __restrict__ A) {
        #pragma unroll
        for (int rt = 0; rt < 2; ++rt)
            #pragma unroll
            for (int ct = 0; ct < 7; ++ct) acc[rt][ct] = (floatx4){0.f, 0.f, 0.f, 0.f};
        short8 bq[4];
        #pragma unroll
        for (int j = 0; j < 4; ++j)
            bq[j] = Bsh[((j % 7) * 8 + (j / 7)) * 64 + lane];   // steps 0..3
        #pragma unroll
        for (int i = 0; i < 56; ++i) {
            const int kc = i / 7, ct = i % 7;
            const short8 bcur = bq[i & 3];
            if (i + 4 < 56) {
                const int i2 = i + 4;
                bq[i & 3] = Bsh[((i2 % 7) * 8 + (i2 / 7)) * 64 + lane];
            }
            if (ct == 0 && kc < 7) {
                #pragma unroll
                for (int rt = 0; rt < 2; ++rt)
                    a1[rt] = A[(2 * w + rt) * 512 + (kc + 1) * 64 + lane];
            }
            acc[0][ct] = __builtin_amdgcn_mfma_f32_16x16x32_bf16(a0[0], bcur, acc[0][ct], 0, 0, 0);
            acc[1][ct] = __builtin_amdgcn_mfma_f32_16x16x32_bf16(a0[1], bcur, acc[1][ct], 0, 0, 0);
            if (ct == 6 && kc < 7) {
                #pragma unroll
                for (int rt = 0; rt < 2; ++rt) a0[rt] = a1[rt];
            }
        }
    };

    // ---------------- GEMM 2 ----------------
    run_gemm(wsA);
    __syncthreads();   // all waves done reading layer-2 B

    // GEMM-3 A(kc=0): issue now, covered by jet-2 math.
    #pragma unroll
    for (int rt = 0; rt < 2; ++rt) a0[rt] = wsA3[(2 * w + rt) * 512 + lane];

    // ---------------- jet 2 (lane-local) -> new B fragments ----------------
    // Wave w's 32 rows are exactly k-tile w; permuted k-order
    // k(qc,j)=16(j>>2)+4qc+(j&3) makes the repack lane-local.
    #pragma unroll
    for (int rt = 0; rt < 2; ++rt) {
        const float4 bb = *(const float4*)(b2 + w * 32 + rt * 16 + qc * 4);
        const float bbv[4] = {bb.x, bb.y, bb.z, bb.w};
        #pragma unroll
        for (int r = 0; r < 4; ++r) {
            float t = fast_tanh(acc[rt][0][r] + bbv[r]);
            float s = 1.f - t * t, c = -2.f * t * s;
            float ux = acc[rt][1][r], uy = acc[rt][2][r], uz = acc[rt][3][r];
            acc[rt][0][r] = t;
            acc[rt][1][r] = s * ux; acc[rt][2][r] = s * uy; acc[rt][3][r] = s * uz;
            acc[rt][4][r] = fmaf(s, acc[rt][4][r], c * ux * ux);
            acc[rt][5][r] = fmaf(s, acc[rt][5][r], c * uy * uy);
            acc[rt][6][r] = fmaf(s, acc[rt][6][r], c * uz * uz);
        }
    }
    #pragma unroll
    for (int s = 0; s < 7; ++s) {
        union { short8 s8; uint_t u4[4]; } v;
        v.u4[0] = pack2bf(acc[0][s][0], acc[0][s][1]);
        v.u4[1] = pack2bf(acc[0][s][2], acc[0][s][3]);
        v.u4[2] = pack2bf(acc[1][s][0], acc[1][s][1]);
        v.u4[3] = pack2bf(acc[1][s][2], acc[1][s][3]);
        Bsh[(s * 8 + w) * 64 + lane] = v.s8;   // kt = w, own lane slot
    }
    __syncthreads();

    // ---------------- GEMM 3 ----------------
    run_gemm(wsA3);

    // ---------------- jet 3 + layer-4 partials (lane-local) ----------------
    float pt[8] = {0.f, 0.f, 0.f, 0.f, 0.f, 0.f, 0.f, 0.f};
    #pragma unroll
    for (int rt = 0; rt < 2; ++rt) {
        const int rb = w * 32 + rt * 16 + qc * 4;
        const float4 bb = *(const float4*)(b3 + rb);
        const float4 w0 = *(const float4*)(W4 + rb);
        const float4 w1 = *(const float4*)(W4 + 256 + rb);
        const float bbv[4] = {bb.x, bb.y, bb.z, bb.w};
        const float w0v[4] = {w0.x, w0.y, w0.z, w0.w};
        const float w1v[4] = {w1.x, w1.y, w1.z, w1.w};
        #pragma unroll
        for (int r = 0; r < 4; ++r) {
            float t = fast_tanh(acc[rt][0][r] + bbv[r]);
            float s = 1.f - t * t, c = -2.f * t * s;
            float ux = acc[rt][1][r], uy = acc[rt][2][r], uz = acc[rt][3][r];
            float hv = t;
            float hxx = fmaf(s, acc[rt][4][r], c * ux * ux);
            float hyy = fmaf(s, acc[rt][5][r], c * uy * uy);
            float hzz = fmaf(s, acc[rt][6][r], c * uz * uz);
            pt[0] = fmaf(w0v[r], hv, pt[0]);
            pt[1] = fmaf(w0v[r], hxx, pt[1]);
            pt[2] = fmaf(w0v[r], hyy, pt[2]);
            pt[3] = fmaf(w0v[r], hzz, pt[3]);
            pt[4] = fmaf(w1v[r], hv, pt[4]);
            pt[5] = fmaf(w1v[r], hxx, pt[5]);
            pt[6] = fmaf(w1v[r], hyy, pt[6]);
            pt[7] = fmaf(w1v[r], hzz, pt[7]);
        }
    }
    #pragma unroll
    for (int k = 0; k < 8; ++k) {
        pt[k] += __shfl_xor(pt[k], 16, 64);
        pt[k] += __shfl_xor(pt[k], 32, 64);
    }
    if (qc == 0) {
        *(float4*)&red[w][n15][0] = make_float4(pt[0], pt[1], pt[2], pt[3]);
        *(float4*)&red[w][n15][4] = make_float4(pt[4], pt[5], pt[6], pt[7]);
    }
    __syncthreads();

    if (tid < 16 && (pbase + tid) < N) {
        const int n = pbase + tid;
        float s8[8] = {0.f, 0.f, 0.f, 0.f, 0.f, 0.f, 0.f, 0.f};
        #pragma unroll
        for (int ww = 0; ww < 8; ++ww)
            #pragma unroll
            for (int k = 0; k < 8; ++k) s8[k] += red[ww][tid][k];
        const float fi = gf[n];
        const float PI = 3.14159265358979323846f;
        const float kw = 2.f * PI * (fi * 500.f + 100.f) / 343.f;
        const float vol = 0.7f * 0.5f * 0.6f;
        const float kk = vol * vol * kw * kw;
        const float cxx = (0.5f * 0.6f) * (0.5f * 0.6f);
        const float cyy = (0.7f * 0.6f) * (0.7f * 0.6f);
        const float czz = (0.7f * 0.5f) * (0.7f * 0.5f);
        const float pr = s8[0] + b4[0];
        const float pim = s8[4] + b4[1];
        out[n]     = 2.0f * (cxx * s8[1] + cyy * s8[2] + czz * s8[3]) + kk * (pr * 2.0f + 0.1f);
        out[N + n] = 1.5f * (cxx * s8[5] + cyy * s8[6] + czz * s8[7]) + kk * (pim * 1.5f - 0.05f);
    }
}

extern "C" void kernel_launch(void* const* d_in, const int* in_sizes, int n_in,
                              void* d_out, int out_size, void* d_ws, size_t ws_size,
                              hipStream_t stream) {
    const float* x = (const float*)d_in[0];
    const float* y = (const float*)d_in[1];
    const float* z = (const float*)d_in[2];
    const float* f = (const float*)d_in[3];
    const float* W1 = (const float*)d_in[4];
    const float* b1 = (const float*)d_in[5];
    const float* W2 = (const float*)d_in[6];
    const float* b2 = (const float*)d_in[7];
    const float* W3 = (const float*)d_in[8];
    const float* b3 = (const float*)d_in[9];
    const float* W4 = (const float*)d_in[10];
    const float* b4 = (const float*)d_in[11];
    float* out = (float*)d_out;
    const int N = in_sizes[0];
    const int grid = (N + PBLK - 1) / PBLK;

    prep_split<<<64, 256, 0, stream>>>(W2, W3, (short8*)d_ws);
    bvp_main<<<grid, 512, 0, stream>>>(x, y, z, f, W1, b1, b2, b3, W4, b4,
                                       (const short8*)d_ws, out, N);
}